// Round 2
// baseline (355.646 us; speedup 1.0000x reference)
//
#include <hip/hip_runtime.h>
#include <hip/hip_fp16.h>

// GCN 2-layer GraphConv (norm='both'), fp32 in/out, fp16 intermediates.
// Round 8: zero random global atomics. Dual binned counting sort:
//   k1:  xw1 (32-row blocks, float4 LDS) || 1024-bin LDS histogram (dst+src)
//   scan_bins: 1024-entry scan (1 block)
//   kB:  two-pass multisplit: dst items -> CSR regions, src items -> count regions
//   kC:  [0,391): per-bin CSR build (col/rowptr/deg/in_norm)
//        [391,782): per-bin src count -> out_norm
//   pull64_xw2 / gcn_pull32: unchanged except out_norm[] replaces hist_s+rsqrt.
//
// ws: int deg[N] | rowptr[N] | f32 in_norm[N] | out_norm[N] |
//     int bin_cnt[1024] | bin_base[1024] | gcur[1024] | col[E] |
//     f16 h1[64N] | h2[32N] ... binbuf[2E] aliases from h2 (dead disjoint in time)

#define BIN_SH 8
#define NBINS_TOT 1024        // dst bins [0,512), src bins [512,1024)
#define SRC_OFF 512
#define KB_EPT 16

// ---- K1: 1024-bin LDS histogram (even blocks) || h1 = x @ W1 (odd) ----
__global__ __launch_bounds__(256) void k1_binhist_xw1(
    const int* __restrict__ src, const int* __restrict__ dst,
    int* __restrict__ bin_cnt,
    const float* __restrict__ x, const float* __restrict__ W,
    __half* __restrict__ h1, int E, int n, int HB, int GX, int EPB) {
  __shared__ __align__(16) char smem[24576];   // 24KB: Ws(16K)+xs(8K) | lcnt(4K)
  float* Ws = (float*)smem;
  float* xs = Ws + 64 * 64;
  int* lcnt = (int*)smem;

  int bid = blockIdx.x;
  int Mn = (HB < GX) ? HB : GX;
  bool isHist;
  int idx;
  if (bid < 2 * Mn) { isHist = !(bid & 1); idx = bid >> 1; }
  else               { isHist = (HB > GX); idx = bid - 2 * Mn + Mn; }

  int t = threadIdx.x;
  if (isHist) {
    for (int i = t; i < NBINS_TOT; i += 256) lcnt[i] = 0;
    __syncthreads();
    int e0 = idx * EPB;
    int e1 = e0 + EPB; if (e1 > E) e1 = E;
    for (int e = e0 + t; e < e1; e += 256) {
      atomicAdd(&lcnt[dst[e] >> BIN_SH], 1);
      atomicAdd(&lcnt[SRC_OFF + (src[e] >> BIN_SH)], 1);
    }
    __syncthreads();
    for (int i = t; i < NBINS_TOT; i += 256)
      if (lcnt[i]) atomicAdd(&bin_cnt[i], lcnt[i]);
    return;
  }
  // xw1: 32 rows per block
#pragma unroll
  for (int i = 0; i < 16; i++) Ws[i * 256 + t] = W[i * 256 + t];
  int row0 = idx * 32;
#pragma unroll
  for (int i = 0; i < 8; i++) {
    int gi = i * 256 + t;
    int r = gi >> 6, k = gi & 63;
    int row = row0 + r;
    xs[gi] = (row < n) ? x[(size_t)row * 64 + k] : 0.0f;
  }
  __syncthreads();
  int c = t & 63, rq = t >> 6;   // rq = wave id; rows rq + 4*rr
  float acc[8] = {0, 0, 0, 0, 0, 0, 0, 0};
#pragma unroll
  for (int kq = 0; kq < 16; kq++) {
    float w0 = Ws[(4 * kq + 0) * 64 + c];
    float w1 = Ws[(4 * kq + 1) * 64 + c];
    float w2 = Ws[(4 * kq + 2) * 64 + c];
    float w3 = Ws[(4 * kq + 3) * 64 + c];
#pragma unroll
    for (int rr = 0; rr < 8; rr++) {
      const float4 xv = *(const float4*)&xs[(rq + rr * 4) * 64 + kq * 4];  // wave-uniform bcast
      acc[rr] += xv.x * w0 + xv.y * w1 + xv.z * w2 + xv.w * w3;
    }
  }
#pragma unroll
  for (int rr = 0; rr < 8; rr++) {
    int row = row0 + rq + rr * 4;
    if (row < n) h1[(size_t)row * 64 + c] = __float2half(acc[rr]);
  }
}

// ---- scan of 1024 bin counts -> exclusive bases; init gcur ----
__global__ __launch_bounds__(1024) void scan_bins(const int* __restrict__ bin_cnt,
                                                  int* __restrict__ bin_base,
                                                  int* __restrict__ gcur) {
  __shared__ int tmp[1024];
  int t = threadIdx.x;
  int v = bin_cnt[t];
  tmp[t] = v;
  __syncthreads();
#pragma unroll
  for (int off = 1; off < 1024; off <<= 1) {
    int val = (t >= off) ? tmp[t - off] : 0;
    __syncthreads();
    tmp[t] += val;
    __syncthreads();
  }
  int ex = tmp[t] - v;
  bin_base[t] = ex;
  gcur[t] = ex;
}

// ---- kB: two-pass multisplit scatter (dst item + src item per edge) ----
__global__ __launch_bounds__(256) void kB_binscatter(
    const int* __restrict__ src, const int* __restrict__ dst,
    int* __restrict__ gcur, int* __restrict__ binbuf, int E) {
  __shared__ int lcnt[1024];
  __shared__ int lbase[1024];
  __shared__ int lpos[1024];
  int t = threadIdx.x;
  for (int i = t; i < 1024; i += 256) lcnt[i] = 0;
  __syncthreads();
  int base = blockIdx.x * (256 * KB_EPT);
#pragma unroll
  for (int i = 0; i < KB_EPT; i++) {
    int e = base + i * 256 + t;
    if (e < E) {
      atomicAdd(&lcnt[dst[e] >> BIN_SH], 1);
      atomicAdd(&lcnt[SRC_OFF + (src[e] >> BIN_SH)], 1);
    }
  }
  __syncthreads();
  for (int i = t; i < 1024; i += 256) {
    int c = lcnt[i];
    lbase[i] = c ? atomicAdd(&gcur[i], c) : 0;
    lpos[i] = 0;
  }
  __syncthreads();
#pragma unroll
  for (int i = 0; i < KB_EPT; i++) {
    int e = base + i * 256 + t;
    if (e < E) {
      int d = dst[e], s = src[e];
      int bd = d >> BIN_SH;
      int rd = atomicAdd(&lpos[bd], 1);
      binbuf[lbase[bd] + rd] = ((d & ((1 << BIN_SH) - 1)) << 17) | s;
      int bs = SRC_OFF + (s >> BIN_SH);
      int rs = atomicAdd(&lpos[bs], 1);
      binbuf[lbase[bs] + rs] = s & ((1 << BIN_SH) - 1);
    }
  }
}

// ---- kC: [0,nbins) dst CSR build; [nbins,2*nbins) src count -> out_norm ----
__global__ __launch_bounds__(256) void kC_build(
    const int* __restrict__ bin_base, const int* __restrict__ binbuf,
    int* __restrict__ col, int* __restrict__ rowptr, int* __restrict__ deg,
    float* __restrict__ in_norm, float* __restrict__ out_norm, int n, int nbins) {
  __shared__ int lcnt[256];
  __shared__ int lptr[256];
  int b = blockIdx.x;
  int t = threadIdx.x;
  if (b >= nbins) {
    // src-bin count
    int sb = b - nbins;
    int ebase = bin_base[SRC_OFF + sb];
    int ecnt = bin_base[SRC_OFF + sb + 1] - ebase;
    lcnt[t] = 0;
    __syncthreads();
    for (int i = t; i < ecnt; i += 256) atomicAdd(&lcnt[binbuf[ebase + i]], 1);
    __syncthreads();
    int node = (sb << BIN_SH) + t;
    if (node < n) out_norm[node] = rsqrtf(fmaxf((float)lcnt[t], 1.0f));
    return;
  }
  int ebase = bin_base[b];
  int ecnt = bin_base[b + 1] - ebase;
  int node0 = b << BIN_SH;
  lcnt[t] = 0;
  __syncthreads();
  for (int i = t; i < ecnt; i += 256) atomicAdd(&lcnt[binbuf[ebase + i] >> 17], 1);
  __syncthreads();
  int cv = lcnt[t];
  lptr[t] = cv;
  __syncthreads();
#pragma unroll
  for (int off = 1; off < 256; off <<= 1) {
    int val = (t >= off) ? lptr[t - off] : 0;
    __syncthreads();
    lptr[t] += val;
    __syncthreads();
  }
  int ex = lptr[t] - cv;
  int node = node0 + t;
  if (node < n) {
    rowptr[node] = ebase + ex;
    deg[node] = cv;
    in_norm[node] = rsqrtf(fmaxf((float)cv, 1.0f));
  }
  __syncthreads();
  lptr[t] = ex;
  __syncthreads();
  for (int i = t; i < ecnt; i += 256) {
    int v = binbuf[ebase + i];
    int r = atomicAdd(&lptr[v >> 17], 1);
    col[ebase + r] = v & 0x1FFFF;   // block-local 16KB region -> L2 merges
  }
}

__device__ inline void acc8h(float* a, uint4 r, float nn) {
  const __half2* hp = reinterpret_cast<const __half2*>(&r);
#pragma unroll
  for (int i = 0; i < 4; i++) {
    float2 f = __half22float2(hp[i]);
    a[2 * i] += nn * f.x;
    a[2 * i + 1] += nn * f.y;
  }
}

// ---- pull64 + fused xw2 ----
__global__ __launch_bounds__(256) void pull64_xw2(
    const int* __restrict__ rowptr, const int* __restrict__ deg,
    const int* __restrict__ col, const __half* __restrict__ h1,
    const float* __restrict__ out_norm, const float* __restrict__ in_norm,
    const float* __restrict__ b1, const float* __restrict__ W2,
    __half* __restrict__ h2, int n) {
  __shared__ float W2s[64 * 32];
  __shared__ float xrow[4][64];
  int t = threadIdx.x;
#pragma unroll
  for (int i = 0; i < 8; i++) W2s[i * 256 + t] = W2[i * 256 + t];

  int w = t >> 6;
  int node = blockIdx.x * 4 + w;
  int l = t & 63;
  int sub = l >> 3, fq = l & 7;

  if (node < n) {
    int beg = rowptr[node];
    int end = beg + deg[node];
    float a0[8] = {0, 0, 0, 0, 0, 0, 0, 0};
    float a1[8] = {0, 0, 0, 0, 0, 0, 0, 0};
    int j = beg;
    for (; j + 16 <= end; j += 16) {
      int s0 = col[j + sub];
      int s1 = col[j + 8 + sub];
      float n0 = out_norm[s0];
      float n1 = out_norm[s1];
      uint4 r0 = ((const uint4*)h1)[(size_t)s0 * 8 + fq];
      uint4 r1 = ((const uint4*)h1)[(size_t)s1 * 8 + fq];
      acc8h(a0, r0, n0);
      acc8h(a1, r1, n1);
    }
    for (; j < end; j += 8) {
      int jj = j + sub;
      if (jj < end) {
        int s = col[jj];
        float nn = out_norm[s];
        uint4 r = ((const uint4*)h1)[(size_t)s * 8 + fq];
        acc8h(a0, r, nn);
      }
    }
    float acc[8];
#pragma unroll
    for (int i = 0; i < 8; i++) acc[i] = a0[i] + a1[i];
#pragma unroll
    for (int d = 8; d <= 32; d <<= 1) {
#pragma unroll
      for (int i = 0; i < 8; i++) acc[i] += __shfl_xor(acc[i], d);
    }
    if (sub == 0) {
      float innv = in_norm[node];
      float onnv = out_norm[node];
      float4 ba = ((const float4*)b1)[fq * 2];
      float4 bb = ((const float4*)b1)[fq * 2 + 1];
      float bv[8] = {ba.x, ba.y, ba.z, ba.w, bb.x, bb.y, bb.z, bb.w};
#pragma unroll
      for (int i = 0; i < 8; i++)
        xrow[w][fq * 8 + i] = fmaxf(acc[i] * innv + bv[i], 0.0f) * onnv;
    }
  }
  __syncthreads();
  if (t < 128) {
    int w2 = t >> 5, c = t & 31;
    int nd = blockIdx.x * 4 + w2;
    if (nd < n) {
      float dot = 0.f;
#pragma unroll 16
      for (int k = 0; k < 64; k++) dot += xrow[w2][k] * W2s[k * 32 + c];
      h2[(size_t)nd * 32 + c] = __float2half(dot);
    }
  }
}

// ---- pull 32 feats + epilogue ----
__global__ __launch_bounds__(256) void gcn_pull32(const int* __restrict__ rowptr,
                                                  const int* __restrict__ deg,
                                                  const int* __restrict__ col,
                                                  const __half* __restrict__ h,
                                                  const float* __restrict__ in_norm,
                                                  const float* __restrict__ b2,
                                                  float* __restrict__ out, int n) {
  int t = threadIdx.x;
  int node = blockIdx.x * 4 + (t >> 6);
  if (node >= n) return;
  int l = t & 63;
  int sub = l >> 3, fq = l & 7;
  int beg = rowptr[node];
  int end = beg + deg[node];
  float a0[4] = {0, 0, 0, 0}, a1[4] = {0, 0, 0, 0};
  int j = beg;
  for (; j + 16 <= end; j += 16) {
    int s0 = col[j + sub];
    int s1 = col[j + 8 + sub];
    uint2 r0 = ((const uint2*)h)[(size_t)s0 * 8 + fq];
    uint2 r1 = ((const uint2*)h)[(size_t)s1 * 8 + fq];
    const __half2* p0 = reinterpret_cast<const __half2*>(&r0);
    const __half2* p1 = reinterpret_cast<const __half2*>(&r1);
#pragma unroll
    for (int i = 0; i < 2; i++) {
      float2 f0 = __half22float2(p0[i]);
      float2 f1 = __half22float2(p1[i]);
      a0[2 * i] += f0.x; a0[2 * i + 1] += f0.y;
      a1[2 * i] += f1.x; a1[2 * i + 1] += f1.y;
    }
  }
  for (; j < end; j += 8) {
    int jj = j + sub;
    if (jj < end) {
      int s = col[jj];
      uint2 r = ((const uint2*)h)[(size_t)s * 8 + fq];
      const __half2* p = reinterpret_cast<const __half2*>(&r);
#pragma unroll
      for (int i = 0; i < 2; i++) {
        float2 f = __half22float2(p[i]);
        a0[2 * i] += f.x; a0[2 * i + 1] += f.y;
      }
    }
  }
  float acc[4];
#pragma unroll
  for (int i = 0; i < 4; i++) acc[i] = a0[i] + a1[i];
#pragma unroll
  for (int d = 8; d <= 32; d <<= 1) {
#pragma unroll
    for (int i = 0; i < 4; i++) acc[i] += __shfl_xor(acc[i], d);
  }
  if (sub == 0) {
    float s = in_norm[node];
    float4 bb = ((const float4*)b2)[fq];
    float4 o;
    o.x = acc[0] * s + bb.x;
    o.y = acc[1] * s + bb.y;
    o.z = acc[2] * s + bb.z;
    o.w = acc[3] * s + bb.w;
    ((float4*)out)[(size_t)node * 8 + fq] = o;
  }
}

extern "C" void kernel_launch(void* const* d_in, const int* in_sizes, int n_in,
                              void* d_out, int out_size, void* d_ws, size_t ws_size,
                              hipStream_t stream) {
  const float* x   = (const float*)d_in[0];
  const int*   src = (const int*)d_in[1];
  const int*   dst = (const int*)d_in[2];
  const float* W1  = (const float*)d_in[3];
  const float* b1  = (const float*)d_in[4];
  const float* W2  = (const float*)d_in[5];
  const float* b2  = (const float*)d_in[6];
  float* out = (float*)d_out;

  const int N = in_sizes[0] / 64;   // 100000
  const int E = in_sizes[1];        // 1600000
  const int NBINS = (N + (1 << BIN_SH) - 1) >> BIN_SH;  // 391

  int* deg       = (int*)d_ws;                 // N
  int* rowptr    = deg + N;                    // N
  float* in_norm = (float*)(rowptr + N);       // N
  float* out_norm= in_norm + N;                // N
  int* bin_cnt   = (int*)(out_norm + N);       // 1024
  int* bin_base  = bin_cnt + 1024;             // 1024
  int* gcur      = bin_base + 1024;            // 1024
  int* col       = gcur + 1024;                // E
  __half* h1 = (__half*)(col + E);             // 64N halves (16B aligned)
  __half* h2 = h1 + (size_t)64 * N;            // 32N halves
  int* binbuf = (int*)h2;                      // 2E ints; dead before pull64 writes h2

  hipMemsetAsync(bin_cnt, 0, 1024 * sizeof(int), stream);

  const int HB = 512;
  const int EPB = (E + HB - 1) / HB;           // 3125
  const int GX = (N + 31) / 32;                // 3125
  k1_binhist_xw1<<<HB + GX, 256, 0, stream>>>(src, dst, bin_cnt, x, W1, h1,
                                              E, N, HB, GX, EPB);
  scan_bins<<<1, 1024, 0, stream>>>(bin_cnt, bin_base, gcur);
  kB_binscatter<<<(E + 256 * KB_EPT - 1) / (256 * KB_EPT), 256, 0, stream>>>(
      src, dst, gcur, binbuf, E);
  kC_build<<<2 * NBINS, 256, 0, stream>>>(bin_base, binbuf, col, rowptr, deg,
                                          in_norm, out_norm, N, NBINS);
  pull64_xw2<<<(N + 3) / 4, 256, 0, stream>>>(rowptr, deg, col, h1, out_norm,
                                              in_norm, b1, W2, h2, N);
  gcn_pull32<<<(N + 3) / 4, 256, 0, stream>>>(rowptr, deg, col, h2, in_norm, b2, out, N);
}

// Round 3
// 259.090 us; speedup vs baseline: 1.3727x; 1.3727x over previous
//
#include <hip/hip_runtime.h>
#include <hip/hip_fp16.h>

// GCN 2-layer GraphConv (norm='both'), fp32 in/out, fp16 intermediates.
// Round 9: fixed-capacity bins kill the histogram/scan stage.
//   kBx: interleaved {kB multisplit scatter (196 blocks)} || {xw1 (6250 blocks)}
//        kB: per-block LDS count -> segment reserve via gcur atomic -> place.
//            dst item = (d&255)<<17 | s (int, region A); src item = s&255 (byte, region B).
//        xw1: round-6 proven 16-row block, acc[4], 52 VGPR.
//   kC:  [0,391): dst-bin CSR build (col compact, rowptr, deg, in_norm);
//        col base = in-block reduction over gcur[0..b).
//        [391,782): src-bin byte count -> out_norm.
//   pull64_xw2 / gcn_pull32: unchanged.
//
// ws: int deg[N] | rowptr[N] | f32 in_norm[N] | out_norm[N] | int gcur[1024] |
//     int col[E] | f16 h1[64N] | f16 h2[32N]
//     binbuf_d[391*CAP ints] aliases h2+ (dead before pull64 writes h2);
//     binbuf_s[391*CAP bytes] follows.  Total ~30.8 MB.

#define BIN_SH 8
#define NBINS 391             // ceil(100000/256)
#define SRC_OFF 512
#define CAP 5120              // mean 4096 + 16 sigma
#define KB_EPT 32             // 8192 edges per kB block

// ---- kBx: kB multisplit (isKB blocks) || h1 = x @ W1 (others) ----
__global__ __launch_bounds__(256) void kBx(
    const int* __restrict__ src, const int* __restrict__ dst,
    int* __restrict__ gcur, int* __restrict__ binbuf_d,
    unsigned char* __restrict__ binbuf_s,
    const float* __restrict__ x, const float* __restrict__ W,
    __half* __restrict__ h1, int E, int n, int NKB, int GX) {
  __shared__ __align__(16) char smem[20480];  // xw1: Ws 16K + xs 4K | kB: 3x4K
  int bid = blockIdx.x;
  int Mn = (NKB < GX) ? NKB : GX;
  bool isKB;
  int idx;
  if (bid < 2 * Mn) { isKB = !(bid & 1); idx = bid >> 1; }
  else               { isKB = (NKB > GX); idx = bid - 2 * Mn + Mn; }

  int t = threadIdx.x;
  if (isKB) {
    int* lcnt = (int*)smem;        // 1024
    int* lbase = lcnt + 1024;      // 1024
    int* lpos = lbase + 1024;      // 1024
    for (int i = t; i < 1024; i += 256) lcnt[i] = 0;
    __syncthreads();
    int base = idx * (256 * KB_EPT);
#pragma unroll 4
    for (int i = 0; i < KB_EPT; i++) {
      int e = base + i * 256 + t;
      if (e < E) {
        atomicAdd(&lcnt[dst[e] >> BIN_SH], 1);
        atomicAdd(&lcnt[SRC_OFF + (src[e] >> BIN_SH)], 1);
      }
    }
    __syncthreads();
    for (int i = t; i < 1024; i += 256) {
      int c = lcnt[i];
      lbase[i] = c ? atomicAdd(&gcur[i], c) : 0;   // reserve; gcur ends as bin count
      lpos[i] = 0;
    }
    __syncthreads();
#pragma unroll 4
    for (int i = 0; i < KB_EPT; i++) {
      int e = base + i * 256 + t;
      if (e < E) {
        int d = dst[e], s = src[e];   // L2-hot re-read
        int bd = d >> BIN_SH;
        int rd = atomicAdd(&lpos[bd], 1);
        binbuf_d[(size_t)bd * CAP + lbase[bd] + rd] = ((d & 255) << 17) | s;
        int bs = SRC_OFF + (s >> BIN_SH);
        int rs = atomicAdd(&lpos[bs], 1);
        binbuf_s[(size_t)(bs - SRC_OFF) * CAP + lbase[bs] + rs] =
            (unsigned char)(s & 255);
      }
    }
    return;
  }
  // ---- xw1 (round-6 proven form): 16 rows/block ----
  float* Ws = (float*)smem;       // 64*64
  float* xs = Ws + 64 * 64;       // 16*64
#pragma unroll
  for (int i = 0; i < 16; i++) Ws[i * 256 + t] = W[i * 256 + t];
  int row0 = idx * 16;
#pragma unroll
  for (int i = 0; i < 4; i++) {
    int gi = i * 256 + t;
    int r = gi >> 6, k = gi & 63;
    int row = row0 + r;
    xs[gi] = (row < n) ? x[(size_t)row * 64 + k] : 0.0f;
  }
  __syncthreads();
  int c = t & 63, rq = t >> 6;
  float acc[4] = {0.f, 0.f, 0.f, 0.f};
#pragma unroll 16
  for (int k = 0; k < 64; k++) {
    float w = Ws[k * 64 + c];
#pragma unroll
    for (int rr = 0; rr < 4; rr++) acc[rr] += xs[(rq + rr * 4) * 64 + k] * w;
  }
#pragma unroll
  for (int rr = 0; rr < 4; rr++) {
    int row = row0 + rq + rr * 4;
    if (row < n) h1[(size_t)row * 64 + c] = __float2half(acc[rr]);
  }
}

// ---- kC: [0,NBINS) dst CSR build; [NBINS,2*NBINS) src count -> out_norm ----
__global__ __launch_bounds__(256) void kC_build(
    const int* __restrict__ gcur, const int* __restrict__ binbuf_d,
    const unsigned char* __restrict__ binbuf_s,
    int* __restrict__ col, int* __restrict__ rowptr, int* __restrict__ deg,
    float* __restrict__ in_norm, float* __restrict__ out_norm, int n) {
  __shared__ int lcnt[256];
  __shared__ int lptr[256];
  __shared__ int red[256];
  int b = blockIdx.x;
  int t = threadIdx.x;
  if (b >= NBINS) {
    // src-bin byte count -> out_norm
    int sb = b - NBINS;
    int cnt = gcur[SRC_OFF + sb];
    const unsigned int* p4 =
        (const unsigned int*)(binbuf_s + (size_t)sb * CAP);
    lcnt[t] = 0;
    __syncthreads();
    int cw = (cnt + 3) >> 2;
    for (int i = t; i < cw; i += 256) {
      unsigned int v = p4[i];
      int rem = cnt - i * 4;
      atomicAdd(&lcnt[v & 255], 1);
      if (rem > 1) atomicAdd(&lcnt[(v >> 8) & 255], 1);
      if (rem > 2) atomicAdd(&lcnt[(v >> 16) & 255], 1);
      if (rem > 3) atomicAdd(&lcnt[v >> 24], 1);
    }
    __syncthreads();
    int node = (sb << BIN_SH) + t;
    if (node < n) out_norm[node] = rsqrtf(fmaxf((float)lcnt[t], 1.0f));
    return;
  }
  // compact col base = sum of dst-bin counts before b
  int part = 0;
  if (t < b) part = gcur[t];
  if (t + 256 < b) part += gcur[t + 256];
  red[t] = part;
  __syncthreads();
#pragma unroll
  for (int off = 128; off > 0; off >>= 1) {
    if (t < off) red[t] += red[t + off];
    __syncthreads();
  }
  int ebase = red[0];
  int cnt = gcur[b];
  const int* items = binbuf_d + (size_t)b * CAP;
  lcnt[t] = 0;
  __syncthreads();
  for (int i = t; i < cnt; i += 256) atomicAdd(&lcnt[items[i] >> 17], 1);
  __syncthreads();
  int cv = lcnt[t];
  lptr[t] = cv;
  __syncthreads();
#pragma unroll
  for (int off = 1; off < 256; off <<= 1) {
    int val = (t >= off) ? lptr[t - off] : 0;
    __syncthreads();
    lptr[t] += val;
    __syncthreads();
  }
  int ex = lptr[t] - cv;
  int node = (b << BIN_SH) + t;
  if (node < n) {
    rowptr[node] = ebase + ex;
    deg[node] = cv;
    in_norm[node] = rsqrtf(fmaxf((float)cv, 1.0f));
  }
  __syncthreads();
  lptr[t] = ex;
  __syncthreads();
  for (int i = t; i < cnt; i += 256) {
    int v = items[i];
    int r = atomicAdd(&lptr[v >> 17], 1);
    col[ebase + r] = v & 0x1FFFF;   // block-local region -> L2 merges
  }
}

__device__ inline void acc8h(float* a, uint4 r, float nn) {
  const __half2* hp = reinterpret_cast<const __half2*>(&r);
#pragma unroll
  for (int i = 0; i < 4; i++) {
    float2 f = __half22float2(hp[i]);
    a[2 * i] += nn * f.x;
    a[2 * i + 1] += nn * f.y;
  }
}

// ---- pull64 + fused xw2 ----
__global__ __launch_bounds__(256) void pull64_xw2(
    const int* __restrict__ rowptr, const int* __restrict__ deg,
    const int* __restrict__ col, const __half* __restrict__ h1,
    const float* __restrict__ out_norm, const float* __restrict__ in_norm,
    const float* __restrict__ b1, const float* __restrict__ W2,
    __half* __restrict__ h2, int n) {
  __shared__ float W2s[64 * 32];
  __shared__ float xrow[4][64];
  int t = threadIdx.x;
#pragma unroll
  for (int i = 0; i < 8; i++) W2s[i * 256 + t] = W2[i * 256 + t];

  int w = t >> 6;
  int node = blockIdx.x * 4 + w;
  int l = t & 63;
  int sub = l >> 3, fq = l & 7;

  if (node < n) {
    int beg = rowptr[node];
    int end = beg + deg[node];
    float a0[8] = {0, 0, 0, 0, 0, 0, 0, 0};
    float a1[8] = {0, 0, 0, 0, 0, 0, 0, 0};
    int j = beg;
    for (; j + 16 <= end; j += 16) {
      int s0 = col[j + sub];
      int s1 = col[j + 8 + sub];
      float n0 = out_norm[s0];
      float n1 = out_norm[s1];
      uint4 r0 = ((const uint4*)h1)[(size_t)s0 * 8 + fq];
      uint4 r1 = ((const uint4*)h1)[(size_t)s1 * 8 + fq];
      acc8h(a0, r0, n0);
      acc8h(a1, r1, n1);
    }
    for (; j < end; j += 8) {
      int jj = j + sub;
      if (jj < end) {
        int s = col[jj];
        float nn = out_norm[s];
        uint4 r = ((const uint4*)h1)[(size_t)s * 8 + fq];
        acc8h(a0, r, nn);
      }
    }
    float acc[8];
#pragma unroll
    for (int i = 0; i < 8; i++) acc[i] = a0[i] + a1[i];
#pragma unroll
    for (int d = 8; d <= 32; d <<= 1) {
#pragma unroll
      for (int i = 0; i < 8; i++) acc[i] += __shfl_xor(acc[i], d);
    }
    if (sub == 0) {
      float innv = in_norm[node];
      float onnv = out_norm[node];
      float4 ba = ((const float4*)b1)[fq * 2];
      float4 bb = ((const float4*)b1)[fq * 2 + 1];
      float bv[8] = {ba.x, ba.y, ba.z, ba.w, bb.x, bb.y, bb.z, bb.w};
#pragma unroll
      for (int i = 0; i < 8; i++)
        xrow[w][fq * 8 + i] = fmaxf(acc[i] * innv + bv[i], 0.0f) * onnv;
    }
  }
  __syncthreads();
  if (t < 128) {
    int w2 = t >> 5, c = t & 31;
    int nd = blockIdx.x * 4 + w2;
    if (nd < n) {
      float dot = 0.f;
#pragma unroll 16
      for (int k = 0; k < 64; k++) dot += xrow[w2][k] * W2s[k * 32 + c];
      h2[(size_t)nd * 32 + c] = __float2half(dot);
    }
  }
}

// ---- pull 32 feats + epilogue ----
__global__ __launch_bounds__(256) void gcn_pull32(const int* __restrict__ rowptr,
                                                  const int* __restrict__ deg,
                                                  const int* __restrict__ col,
                                                  const __half* __restrict__ h,
                                                  const float* __restrict__ in_norm,
                                                  const float* __restrict__ b2,
                                                  float* __restrict__ out, int n) {
  int t = threadIdx.x;
  int node = blockIdx.x * 4 + (t >> 6);
  if (node >= n) return;
  int l = t & 63;
  int sub = l >> 3, fq = l & 7;
  int beg = rowptr[node];
  int end = beg + deg[node];
  float a0[4] = {0, 0, 0, 0}, a1[4] = {0, 0, 0, 0};
  int j = beg;
  for (; j + 16 <= end; j += 16) {
    int s0 = col[j + sub];
    int s1 = col[j + 8 + sub];
    uint2 r0 = ((const uint2*)h)[(size_t)s0 * 8 + fq];
    uint2 r1 = ((const uint2*)h)[(size_t)s1 * 8 + fq];
    const __half2* p0 = reinterpret_cast<const __half2*>(&r0);
    const __half2* p1 = reinterpret_cast<const __half2*>(&r1);
#pragma unroll
    for (int i = 0; i < 2; i++) {
      float2 f0 = __half22float2(p0[i]);
      float2 f1 = __half22float2(p1[i]);
      a0[2 * i] += f0.x; a0[2 * i + 1] += f0.y;
      a1[2 * i] += f1.x; a1[2 * i + 1] += f1.y;
    }
  }
  for (; j < end; j += 8) {
    int jj = j + sub;
    if (jj < end) {
      int s = col[jj];
      uint2 r = ((const uint2*)h)[(size_t)s * 8 + fq];
      const __half2* p = reinterpret_cast<const __half2*>(&r);
#pragma unroll
      for (int i = 0; i < 2; i++) {
        float2 f = __half22float2(p[i]);
        a0[2 * i] += f.x; a0[2 * i + 1] += f.y;
      }
    }
  }
  float acc[4];
#pragma unroll
  for (int i = 0; i < 4; i++) acc[i] = a0[i] + a1[i];
#pragma unroll
  for (int d = 8; d <= 32; d <<= 1) {
#pragma unroll
    for (int i = 0; i < 4; i++) acc[i] += __shfl_xor(acc[i], d);
  }
  if (sub == 0) {
    float s = in_norm[node];
    float4 bb = ((const float4*)b2)[fq];
    float4 o;
    o.x = acc[0] * s + bb.x;
    o.y = acc[1] * s + bb.y;
    o.z = acc[2] * s + bb.z;
    o.w = acc[3] * s + bb.w;
    ((float4*)out)[(size_t)node * 8 + fq] = o;
  }
}

extern "C" void kernel_launch(void* const* d_in, const int* in_sizes, int n_in,
                              void* d_out, int out_size, void* d_ws, size_t ws_size,
                              hipStream_t stream) {
  const float* x   = (const float*)d_in[0];
  const int*   src = (const int*)d_in[1];
  const int*   dst = (const int*)d_in[2];
  const float* W1  = (const float*)d_in[3];
  const float* b1  = (const float*)d_in[4];
  const float* W2  = (const float*)d_in[5];
  const float* b2  = (const float*)d_in[6];
  float* out = (float*)d_out;

  const int N = in_sizes[0] / 64;   // 100000
  const int E = in_sizes[1];        // 1600000

  int* deg        = (int*)d_ws;                // N
  int* rowptr     = deg + N;                   // N
  float* in_norm  = (float*)(rowptr + N);      // N
  float* out_norm = in_norm + N;               // N
  int* gcur       = (int*)(out_norm + N);      // 1024
  int* col        = gcur + 1024;               // E (compact)
  __half* h1 = (__half*)(col + E);             // 64N halves
  __half* h2 = h1 + (size_t)64 * N;            // 32N halves
  int* binbuf_d = (int*)h2;                    // 391*CAP ints (aliases h2+, dead later)
  unsigned char* binbuf_s =
      (unsigned char*)(binbuf_d + (size_t)NBINS * CAP);  // 391*CAP bytes

  hipMemsetAsync(gcur, 0, 1024 * sizeof(int), stream);

  const int NKB = (E + 256 * KB_EPT - 1) / (256 * KB_EPT);  // 196
  const int GX = (N + 15) / 16;                             // 6250
  kBx<<<NKB + GX, 256, 0, stream>>>(src, dst, gcur, binbuf_d, binbuf_s,
                                    x, W1, h1, E, N, NKB, GX);
  kC_build<<<2 * NBINS, 256, 0, stream>>>(gcur, binbuf_d, binbuf_s, col, rowptr,
                                          deg, in_norm, out_norm, N);
  pull64_xw2<<<(N + 3) / 4, 256, 0, stream>>>(rowptr, deg, col, h1, out_norm,
                                              in_norm, b1, W2, h2, N);
  gcn_pull32<<<(N + 3) / 4, 256, 0, stream>>>(rowptr, deg, col, h2, in_norm, b2, out, N);
}